// Round 3
// baseline (242.228 us; speedup 1.0000x reference)
//
#include <hip/hip_runtime.h>
#include <math.h>

#define WIN 11
#define IMG_H 384
#define IMG_W 512
#define OUT_H (IMG_H - WIN + 1)   // 374
#define OUT_W (IMG_W - WIN + 1)   // 502
#define RPW 2                     // output rows per wave
#define NPAIRS 187                // row-pairs per image (374 = 2*187)
#define NIMG 48
#define ROW_BYTES (IMG_W * 4)     // 2048
#define SLOT_BYTES (2 * ROW_BYTES)    // X+Y per row slot = 4096
#define NBUCKETS 256

// ---- kernel A (ring) geometry ----
#define A_WPB 8                   // waves per block (512 threads)
#define GRP_PAIRS 8               // pairs per group (1 per wave)
#define GRPS_PER_IMG 24           // 23 full groups + tail of 3 pairs
#define NUNITS (NIMG * GRPS_PER_IMG)  // 1152 = 4.5 * 256
#define A_NBLOCKS 256             // 1 block per CU
#define RING 32                   // ring slots; slot = row & 31
#define RING_LDS (RING * SLOT_BYTES)  // 131072 = 128 KiB (proven size)

// ---- kernel B (r13 fallback) geometry ----
#define B_WPB 4
#define B_ROWS_PB (RPW * B_WPB)       // 8
#define B_PB_PER_IMG 47
#define B_NBLOCKS (NIMG * B_PB_PER_IMG)  // 2256 = 8*282
#define B_BPX 282
#define B_STAGE_ROWS (B_ROWS_PB + WIN - 1) // 18
#define B_LDS (B_STAGE_ROWS * SLOT_BYTES)  // 73728 (harness-proven)

typedef float v2 __attribute__((ext_vector_type(2)));

struct GaussW { float g[WIN]; };

// Fire-and-forget global->LDS DMA, 16B per lane. LDS dest is wave-uniform
// base + 16*lane (HW rule); global src is per-lane (m173 pre-permute).
__device__ __forceinline__ void gload16(const void* g, void* l) {
    __builtin_amdgcn_global_load_lds(
        (const __attribute__((address_space(1))) unsigned int*)g,
        (__attribute__((address_space(3))) unsigned int*)l,
        16, 0, 0);
}

// Stage NCH 16B-chunks per wave into the 32-slot ring. Chunk c = wave+8*i ->
// (rowOff = c>>2, tensor = (c>>1)&1, parity = c&1). Even chunks of a row land
// at [0,1024) of the tensor half, odd at [1024,2048), so compute-phase
// ds_read_b128 at lane*16 is the sequential conflict-free pattern.
// Slot comes from the UNCLAMPED row (ring invariant slot = row & 31);
// address clamps to the last image row (junk prefetches near image end).
template<int NCH>
__device__ __forceinline__ void stage_ring(const char* Xi, const char* Yi,
                                           int row0, char* smem,
                                           int wave, int lane)
{
    #pragma unroll
    for (int i = 0; i < NCH; ++i) {
        const int c  = wave + 8 * i;
        const int ro = c >> 2;
        const int t  = (c >> 1) & 1;
        const int e  = c & 1;
        const int rowu = row0 + ro;
        const int slot = rowu & (RING - 1);
        const int row  = rowu < IMG_H ? rowu : (IMG_H - 1);
        const char* src = (t ? Yi : Xi) + (size_t)row * ROW_BYTES
                          + lane * 32 + e * 16;
        char* dst = smem + slot * SLOT_BYTES + t * ROW_BYTES + e * 1024
                    + lane * 16;
        gload16(src, dst);
    }
}

__device__ __forceinline__ v2 shfl_v2(v2 v, int src) {
    v2 r; r.x = __shfl(v.x, src, 64); r.y = __shfl(v.y, src, 64); return r;
}

__device__ __forceinline__ void horiz11_v2(const v2 (&A)[8], v2 (&out)[8],
                                           int lane, const GaussW& gw)
{
    v2 V[18];
    #pragma unroll
    for (int j = 0; j < 8; ++j) V[j] = A[j];
    #pragma unroll
    for (int j = 0; j < 8; ++j) V[8 + j] = shfl_v2(A[j], lane + 1);
    V[16] = shfl_v2(A[0], lane + 2);
    V[17] = shfl_v2(A[1], lane + 2);
    #pragma unroll
    for (int j = 0; j < 8; ++j) {
        v2 o = 0.f;
        #pragma unroll
        for (int k = 0; k < WIN; ++k) {
            v2 g = gw.g[k];
            o = __builtin_elementwise_fma(g, V[j + k], o);
        }
        out[j] = o;
    }
}

__device__ __forceinline__ void horiz11_f(const float (&A)[8], float (&out)[8],
                                          int lane, const GaussW& gw)
{
    float V[18];
    #pragma unroll
    for (int j = 0; j < 8; ++j) V[j] = A[j];
    #pragma unroll
    for (int j = 0; j < 8; ++j) V[8 + j] = __shfl(A[j], lane + 1, 64);
    V[16] = __shfl(A[0], lane + 2, 64);
    V[17] = __shfl(A[1], lane + 2, 64);
    #pragma unroll
    for (int j = 0; j < 8; ++j) {
        float o = 0.f;
        #pragma unroll
        for (int k = 0; k < WIN; ++k) o = fmaf(gw.g[k], V[j + k], o);
        out[j] = o;
    }
}

// Shared vertical+horizontal+epilogue body (identical math in A and B).
__device__ __forceinline__ float compute_pair(const char* lbase,
                                              const int (&offs)[RPW + WIN - 1],
                                              int lane, const GaussW& gw)
{
    v2 a01[RPW][8], a23[RPW][8];
    float a4[RPW][8];
    #pragma unroll
    for (int r = 0; r < RPW; ++r)
        #pragma unroll
        for (int j = 0; j < 8; ++j) { a01[r][j] = 0.f; a23[r][j] = 0.f; a4[r][j] = 0.f; }

    #pragma unroll
    for (int k = 0; k < RPW + WIN - 1; ++k) {   // 12 rows, all LDS
        const char* lr = lbase + offs[k];
        float4 xa = *(const float4*)(lr);
        float4 xb = *(const float4*)(lr + 1024);
        float4 ya = *(const float4*)(lr + 2048);
        float4 yb = *(const float4*)(lr + 3072);
        v2 p[8] = {{xa.x, ya.x}, {xa.y, ya.y}, {xa.z, ya.z}, {xa.w, ya.w},
                   {xb.x, yb.x}, {xb.y, yb.y}, {xb.z, yb.z}, {xb.w, yb.w}};
        #pragma unroll
        for (int r = 0; r < RPW; ++r) {
            if (k - r >= 0 && k - r < WIN) {     // compile-time after unroll
                v2 g = gw.g[k - r];
                #pragma unroll
                for (int j = 0; j < 8; ++j) {
                    v2 q = p[j];
                    a01[r][j] = __builtin_elementwise_fma(g, q, a01[r][j]);
                    v2 t = g * q;
                    a23[r][j] = __builtin_elementwise_fma(t, q, a23[r][j]);
                    a4[r][j]  = fmaf(t.x, q.y, a4[r][j]);
                }
            }
        }
    }

    const int c0 = lane << 3;
    const float C1 = 1e-4f, C2 = 9e-4f;
    float sum = 0.f;
    #pragma unroll
    for (int r = 0; r < RPW; ++r) {
        v2 h01[8], h23[8];
        float h4[8];
        horiz11_v2(a01[r], h01, lane, gw);
        horiz11_v2(a23[r], h23, lane, gw);
        horiz11_f (a4[r],  h4,  lane, gw);
        #pragma unroll
        for (int j = 0; j < 8; ++j) {
            v2 mu = h01[j];
            v2 sq = mu * mu;
            float m12 = mu.x * mu.y;
            v2 sig = h23[j] - sq;
            float s12 = h4[j] - m12;
            float num = fmaf(2.f, m12, C1) * fmaf(2.f, s12, C2);
            float den = (sq.x + sq.y + C1) * (sig.x + sig.y + C2);
            float ssim = num * __builtin_amdgcn_rcpf(den);
            sum += (c0 + j < OUT_W) ? ssim : 0.f;
        }
    }
    return sum;
}

// ---------------- kernel A: persistent 32-slot ring pipeline ----------------
// 256 blocks x 8 waves (1 block/CU). Each block sweeps ~4.5 contiguous
// 16-row groups through a 32-slot LDS row ring (slot = row & 31). Per group:
// issue P1 (6 rows, 3 DMAs/wave), counted vmcnt(3) (waits P2 of the previous
// group, keeps P1 in flight), barrier, vertical pass (only LDS reader),
// barrier, issue P2 (10 rows, 5 DMAs/wave, overwrites the 16 rows just
// retired) which drains under the register-only horizontal pass. Breaks
// r13's resident-block phase lock: stage latency hides under compute inside
// one block, and ring reuse cuts staged bytes 2.25x -> ~1.1x of input.
__global__ __launch_bounds__(512) void ssim_ring_kernel(
    const float* __restrict__ X, const float* __restrict__ Y,
    double* __restrict__ accum, GaussW gw)
{
    extern __shared__ char smem[];
    const int wave = threadIdx.x >> 6;
    const int lane = threadIdx.x & 63;

    int u          = (9 * blockIdx.x) >> 1;        // 1152/256 = 4.5 units/block
    const int uend = (9 * (blockIdx.x + 1)) >> 1;

    bool first = true;
    for (; u < uend; ++u) {
        const int img = u / GRPS_PER_IMG;
        const int grp = u - img * GRPS_PER_IMG;
        const char* Xi = (const char*)X + (size_t)img * IMG_H * ROW_BYTES;
        const char* Yi = (const char*)Y + (size_t)img * IMG_H * ROW_BYTES;
        const int rb = grp * 16;                   // base input row of group

        if (first || grp == 0) {
            // cold (re)warm: drain old DMAs (write-write race vs new epoch),
            // full sync, then stage the 26-row live window rb..rb+25.
            asm volatile("s_waitcnt vmcnt(0)" ::: "memory");
            __syncthreads();
            stage_ring<13>(Xi, Yi, rb, smem, wave, lane);
            first = false;
        }

        // P1: rows rb+26..rb+31 into the 6 free slots (live window = 26).
        stage_ring<3>(Xi, Yi, rb + 26, smem, wave, lane);
        // Wait everything older than P1 (i.e. P2 of prev group / warm-up 13);
        // P1's 3 DMAs stay in flight.
        asm volatile("s_waitcnt vmcnt(3)" ::: "memory");
        __builtin_amdgcn_sched_barrier(0);
        __builtin_amdgcn_s_barrier();
        __builtin_amdgcn_sched_barrier(0);

        const int pairs_in_grp = (grp < GRPS_PER_IMG - 1) ? GRP_PAIRS : 3;
        const bool valid = wave < pairs_in_grp;

        float sum = 0.f;
        if (valid) {
            int offs[RPW + WIN - 1];
            #pragma unroll
            for (int k = 0; k < RPW + WIN - 1; ++k)
                offs[k] = ((rb + 2 * wave + k) & (RING - 1)) * SLOT_BYTES;
            sum = compute_pair(smem + lane * 16, offs, lane, gw);
        }

        // All vertical ds_reads consumed (compiler waits lgkmcnt before the
        // FMAs) -> after this barrier, rows rb..rb+15 are dead; P2 may
        // overwrite rows rb..rb+9's slots.
        __builtin_amdgcn_sched_barrier(0);
        __builtin_amdgcn_s_barrier();
        __builtin_amdgcn_sched_barrier(0);
        stage_ring<5>(Xi, Yi, rb + 32, smem, wave, lane);  // P2: rb+32..rb+41

        if (valid) {
            #pragma unroll
            for (int off = 32; off; off >>= 1)
                sum += __shfl_down(sum, off, 64);
            if (lane == 0) {
                const int P = img * NPAIRS + grp * GRP_PAIRS + wave;
                atomicAdd(&accum[P & (NBUCKETS - 1)], (double)sum);
            }
        }
    }
    // Drain trailing P2 DMAs before endpgm (LDS dealloc safety).
    asm volatile("s_waitcnt vmcnt(0)" ::: "memory");
}

// ---------------- kernel B: r13 one-shot staging (proven fallback) ----------
__global__ __launch_bounds__(256) void ssim_block_kernel(
    const float* __restrict__ X, const float* __restrict__ Y,
    double* __restrict__ accum, GaussW gw)
{
    extern __shared__ char smem[];
    const int wave = threadIdx.x >> 6;
    const int lane = threadIdx.x & 63;

    const int id = blockIdx.x;
    const int wb = (id & 7) * B_BPX + (id >> 3);   // XCD swizzle (bijective)
    const int img = wb / B_PB_PER_IMG;
    const int pb  = wb - img * B_PB_PER_IMG;
    const int r0  = pb * B_ROWS_PB;

    {
        const int t = wave >> 1, e = wave & 1;
        const float* tb = t ? Y : X;
        const char* src = (const char*)(tb + (size_t)img * IMG_H * IMG_W)
                          + lane * 32 + e * 16;
        char* dst = smem + t * ROW_BYTES + e * 1024 + lane * 16;
        #pragma unroll
        for (int r = 0; r < B_STAGE_ROWS; ++r) {
            int row = r0 + r;
            row = row < IMG_H ? row : (IMG_H - 1);
            gload16(src + (size_t)row * ROW_BYTES, dst + r * SLOT_BYTES);
        }
    }
    asm volatile("s_waitcnt vmcnt(0)" ::: "memory");
    __syncthreads();

    const int pair = pb * B_WPB + wave;
    if (pair < NPAIRS) {
        int offs[RPW + WIN - 1];
        #pragma unroll
        for (int k = 0; k < RPW + WIN - 1; ++k)
            offs[k] = (2 * wave + k) * SLOT_BYTES;
        float sum = compute_pair(smem + lane * 16, offs, lane, gw);

        #pragma unroll
        for (int off = 32; off; off >>= 1)
            sum += __shfl_down(sum, off, 64);
        if (lane == 0) {
            const int P = img * NPAIRS + pair;
            atomicAdd(&accum[P & (NBUCKETS - 1)], (double)sum);
        }
    }
}

__global__ void ssim_finalize_kernel(const double* __restrict__ accum,
                                     float* __restrict__ out, double inv_count)
{
    const int lane = threadIdx.x;
    double s = 0.0;
    for (int i = lane; i < NBUCKETS; i += 64) s += accum[i];
    #pragma unroll
    for (int off = 32; off; off >>= 1)
        s += __shfl_down(s, off, 64);
    if (lane == 0) out[0] = (float)(1.0 - s * inv_count);
}

extern "C" void kernel_launch(void* const* d_in, const int* in_sizes, int n_in,
                              void* d_out, int out_size, void* d_ws, size_t ws_size,
                              hipStream_t stream) {
    const float* X = (const float*)d_in[0];
    const float* Y = (const float*)d_in[1];
    float* out = (float*)d_out;
    double* accum = (double*)d_ws;

    GaussW gw;
    {
        double g[WIN], ssum = 0.0;
        for (int i = 0; i < WIN; ++i) {
            double d = (double)i - WIN / 2;
            g[i] = exp(-(d * d) / (2.0 * 1.5 * 1.5));
            ssum += g[i];
        }
        for (int i = 0; i < WIN; ++i) gw.g[i] = (float)(g[i] / ssum);
    }

    // Opt-in LDS (host-side, once, not a stream op). If 128 KiB is rejected,
    // fall back to the r13 kernel at its proven 72 KiB.
    static int s_mode = -1;
    if (s_mode < 0) {
        hipError_t e = hipFuncSetAttribute((const void*)ssim_ring_kernel,
                           hipFuncAttributeMaxDynamicSharedMemorySize, RING_LDS);
        s_mode = (e == hipSuccess) ? 0 : 1;
        if (s_mode == 1)
            (void)hipFuncSetAttribute((const void*)ssim_block_kernel,
                       hipFuncAttributeMaxDynamicSharedMemorySize, B_LDS);
    }

    // d_ws is re-poisoned 0xAA before every call — zero the buckets.
    hipMemsetAsync(accum, 0, NBUCKETS * sizeof(double), stream);

    if (s_mode == 0)
        ssim_ring_kernel<<<A_NBLOCKS, 64 * A_WPB, RING_LDS, stream>>>(X, Y, accum, gw);
    else
        ssim_block_kernel<<<B_NBLOCKS, 64 * B_WPB, B_LDS, stream>>>(X, Y, accum, gw);

    const double inv_count = 1.0 / ((double)NIMG * OUT_H * OUT_W);
    ssim_finalize_kernel<<<1, 64, 0, stream>>>(accum, out, inv_count);
}

// Round 6
// 156.009 us; speedup vs baseline: 1.5527x; 1.5527x over previous
//
#include <hip/hip_runtime.h>
#include <math.h>

#define WIN 11
#define IMG_H 384
#define IMG_W 512
#define OUT_H (IMG_H - WIN + 1)   // 374
#define OUT_W (IMG_W - WIN + 1)   // 502
#define RPW 4                     // output rows per wave (r18: was 2)
#define UNITS_PER_IMG 94          // 93 full 4-row units + 1 clamped tail unit
#define NIMG 48
#define TOTAL_UNITS (UNITS_PER_IMG * NIMG)   // 4512
#define WPB 4                     // independent waves per block (no barriers)
#define NBLOCKS (TOTAL_UNITS / WPB)          // 1128 = 8 * 141, exact
#define BPX 141                   // blocks per XCD
#define ROW_BYTES (IMG_W * 4)     // 2048
#define NBUCKETS 256

typedef float v2 __attribute__((ext_vector_type(2)));

struct GaussW { float g[WIN]; };

__device__ __forceinline__ v2 shfl_v2(v2 v, int src) {
    v2 r; r.x = __shfl(v.x, src, 64); r.y = __shfl(v.y, src, 64); return r;
}

__device__ __forceinline__ void horiz11_v2(const v2 (&A)[8], v2 (&out)[8],
                                           int lane, const GaussW& gw)
{
    v2 V[18];
    #pragma unroll
    for (int j = 0; j < 8; ++j) V[j] = A[j];
    #pragma unroll
    for (int j = 0; j < 8; ++j) V[8 + j] = shfl_v2(A[j], lane + 1);
    V[16] = shfl_v2(A[0], lane + 2);
    V[17] = shfl_v2(A[1], lane + 2);
    #pragma unroll
    for (int j = 0; j < 8; ++j) {
        v2 o = 0.f;
        #pragma unroll
        for (int k = 0; k < WIN; ++k) {
            v2 g = gw.g[k];
            o = __builtin_elementwise_fma(g, V[j + k], o);  // v_pk_fma_f32
        }
        out[j] = o;
    }
}

__device__ __forceinline__ void horiz11_f(const float (&A)[8], float (&out)[8],
                                          int lane, const GaussW& gw)
{
    float V[18];
    #pragma unroll
    for (int j = 0; j < 8; ++j) V[j] = A[j];
    #pragma unroll
    for (int j = 0; j < 8; ++j) V[8 + j] = __shfl(A[j], lane + 1, 64);
    V[16] = __shfl(A[0], lane + 2, 64);
    V[17] = __shfl(A[1], lane + 2, 64);
    #pragma unroll
    for (int j = 0; j < 8; ++j) {
        float o = 0.f;
        #pragma unroll
        for (int k = 0; k < WIN; ++k) o = fmaf(gw.g[k], V[j + k], o);
        out[j] = o;
    }
}

// r18 vs r12: RPW 2 -> 4. Each wave now produces 4 output rows from 14
// input rows (3.5x input amplification vs 6x), so per-output-row load
// count and row-packing overhead drop ~42%, at the same measured residency
// (VGPR ~200 -> 2 waves/SIMD, which is what r12 actually achieved at
// VGPR=76 anyway per OccupancyPercent=24). Grid: 4512 waves = 1128 blocks
// = 8*141, exact (no pad waves). Tail: the last unit per image clamps
// r0 to 370 and masks rows it doesn't own (wave-uniform branch, loads all
// in bounds: max input row = 370+13 = 383). Plain HIP loads only — the
// counted-vmcnt asm pipeline (r16/r17) is parked after two container
// failures; this round isolates the per-output-overhead lever instead.
__global__ __launch_bounds__(256) void ssim_fused_kernel(
    const float* __restrict__ X, const float* __restrict__ Y,
    double* __restrict__ accum, GaussW gw)
{
    const int wave = threadIdx.x >> 6;
    const int lane = threadIdx.x & 63;

    // Block-level XCD swizzle (bijective: 1128 = 8*141); waves in a block
    // take adjacent 4-row units (shared halo rows hit L1/L2).
    const int id = blockIdx.x;
    const int wb = (id & 7) * BPX + (id >> 3);
    const int U  = wb * WPB + wave;        // global unit index, < 4512 exactly

    const int img = U / UNITS_PER_IMG;
    const int u   = U - img * UNITS_PER_IMG;
    const int rf  = u * RPW;               // first output row this unit OWNS
    const int r0  = (rf <= OUT_H - RPW) ? rf : (OUT_H - RPW);  // tail: 370
    const int c0  = lane << 3;             // this lane's 8 columns
    const float* __restrict__ Xb = X + ((size_t)img * IMG_H + r0) * IMG_W + c0;
    const float* __restrict__ Yb = Y + ((size_t)img * IMG_H + r0) * IMG_W + c0;

    // Accumulators: a01 = {m1,m2}, a23 = {xx,yy}, a4 = xy (tensor-packed)
    v2 a01[RPW][8], a23[RPW][8];
    float a4[RPW][8];
    #pragma unroll
    for (int r = 0; r < RPW; ++r)
        #pragma unroll
        for (int j = 0; j < 8; ++j) { a01[r][j] = 0.f; a23[r][j] = 0.f; a4[r][j] = 0.f; }

    #pragma unroll
    for (int k = 0; k < RPW + WIN - 1; ++k) {   // 14 input rows
        const float* rx = Xb + (size_t)k * IMG_W;
        const float* ry = Yb + (size_t)k * IMG_W;
        float4 xa = *(const float4*)(rx);
        float4 xb = *(const float4*)(rx + 4);
        float4 ya = *(const float4*)(ry);
        float4 yb = *(const float4*)(ry + 4);
        v2 p[8] = {{xa.x, ya.x}, {xa.y, ya.y}, {xa.z, ya.z}, {xa.w, ya.w},
                   {xb.x, yb.x}, {xb.y, yb.y}, {xb.z, yb.z}, {xb.w, yb.w}};
        #pragma unroll
        for (int r = 0; r < RPW; ++r) {
            if (k - r >= 0 && k - r < WIN) {     // compile-time after unroll
                v2 g = gw.g[k - r];
                #pragma unroll
                for (int j = 0; j < 8; ++j) {
                    v2 q = p[j];
                    a01[r][j] = __builtin_elementwise_fma(g, q, a01[r][j]);
                    v2 t = g * q;                                  // {gx, gy}
                    a23[r][j] = __builtin_elementwise_fma(t, q, a23[r][j]);
                    a4[r][j]  = fmaf(t.x, q.y, a4[r][j]);          // g*x*y
                }
            }
        }
    }

    // ---- horizontal + epilogue per owned row ----
    const float C1 = 1e-4f, C2 = 9e-4f;
    float sum = 0.f;
    #pragma unroll
    for (int r = 0; r < RPW; ++r) {
        if (r0 + r >= rf) {                 // wave-uniform ownership mask
            v2 h01[8], h23[8];
            float h4[8];
            horiz11_v2(a01[r], h01, lane, gw);
            horiz11_v2(a23[r], h23, lane, gw);
            horiz11_f (a4[r],  h4,  lane, gw);
            #pragma unroll
            for (int j = 0; j < 8; ++j) {
                v2 mu = h01[j];
                v2 sq = mu * mu;                    // {mu1², mu2²}
                float m12 = mu.x * mu.y;
                v2 sig = h23[j] - sq;               // {s1, s2}
                float s12 = h4[j] - m12;
                float num = fmaf(2.f, m12, C1) * fmaf(2.f, s12, C2);
                float den = (sq.x + sq.y + C1) * (sig.x + sig.y + C2);
                float ssim = num * __builtin_amdgcn_rcpf(den);
                sum += (c0 + j < OUT_W) ? ssim : 0.f;
            }
        }
    }

    // ---- wave reduction -> one f64 atomic per wave, bucketed ----
    #pragma unroll
    for (int off = 32; off; off >>= 1)
        sum += __shfl_down(sum, off, 64);
    if (lane == 0)
        atomicAdd(&accum[U & (NBUCKETS - 1)], (double)sum);
}

__global__ void ssim_finalize_kernel(const double* __restrict__ accum,
                                     float* __restrict__ out, double inv_count)
{
    const int lane = threadIdx.x;
    double s = 0.0;
    for (int i = lane; i < NBUCKETS; i += 64) s += accum[i];
    #pragma unroll
    for (int off = 32; off; off >>= 1)
        s += __shfl_down(s, off, 64);
    if (lane == 0) out[0] = (float)(1.0 - s * inv_count);
}

extern "C" void kernel_launch(void* const* d_in, const int* in_sizes, int n_in,
                              void* d_out, int out_size, void* d_ws, size_t ws_size,
                              hipStream_t stream) {
    const float* X = (const float*)d_in[0];
    const float* Y = (const float*)d_in[1];
    float* out = (float*)d_out;
    double* accum = (double*)d_ws;

    GaussW gw;
    {
        double g[WIN], ssum = 0.0;
        for (int i = 0; i < WIN; ++i) {
            double d = (double)i - WIN / 2;
            g[i] = exp(-(d * d) / (2.0 * 1.5 * 1.5));
            ssum += g[i];
        }
        for (int i = 0; i < WIN; ++i) gw.g[i] = (float)(g[i] / ssum);
    }

    // d_ws is re-poisoned 0xAA before every call — zero the buckets.
    hipMemsetAsync(accum, 0, NBUCKETS * sizeof(double), stream);

    ssim_fused_kernel<<<NBLOCKS, 64 * WPB, 0, stream>>>(X, Y, accum, gw);

    const double inv_count = 1.0 / ((double)NIMG * OUT_H * OUT_W);
    ssim_finalize_kernel<<<1, 64, 0, stream>>>(accum, out, inv_count);
}

// Round 7
// 129.049 us; speedup vs baseline: 1.8770x; 1.2089x over previous
//
#include <hip/hip_runtime.h>
#include <math.h>

#define WIN 11
#define IMG_H 384
#define IMG_W 512
#define OUT_H (IMG_H - WIN + 1)   // 374
#define OUT_W (IMG_W - WIN + 1)   // 502
#define RPW 2                     // output rows per wave (r18's RPW=4 refuted:
                                  // VGPR 224 -> occupancy tier halved -> 82us)
#define NPAIRS 187                // per image (exact: 374 = 2*187)
#define NIMG 48
#define TOTAL_PAIRS (NPAIRS * NIMG)   // 8976
#define WPB 8                     // r19: 8 independent waves per block (was 4)
#define NBLOCKS 1128              // ceil(8976/8)=1122 padded to 8*141 for swizzle
#define BPX 141                   // blocks per XCD
#define ROW_BYTES (IMG_W * 4)     // 2048
#define NBUCKETS 256

typedef float v2 __attribute__((ext_vector_type(2)));

struct GaussW { float g[WIN]; };

__device__ __forceinline__ v2 shfl_v2(v2 v, int src) {
    v2 r; r.x = __shfl(v.x, src, 64); r.y = __shfl(v.y, src, 64); return r;
}

__device__ __forceinline__ void horiz11_v2(const v2 (&A)[8], v2 (&out)[8],
                                           int lane, const GaussW& gw)
{
    v2 V[18];
    #pragma unroll
    for (int j = 0; j < 8; ++j) V[j] = A[j];
    #pragma unroll
    for (int j = 0; j < 8; ++j) V[8 + j] = shfl_v2(A[j], lane + 1);
    V[16] = shfl_v2(A[0], lane + 2);
    V[17] = shfl_v2(A[1], lane + 2);
    #pragma unroll
    for (int j = 0; j < 8; ++j) {
        v2 o = 0.f;
        #pragma unroll
        for (int k = 0; k < WIN; ++k) {
            v2 g = gw.g[k];
            o = __builtin_elementwise_fma(g, V[j + k], o);  // v_pk_fma_f32
        }
        out[j] = o;
    }
}

__device__ __forceinline__ void horiz11_f(const float (&A)[8], float (&out)[8],
                                          int lane, const GaussW& gw)
{
    float V[18];
    #pragma unroll
    for (int j = 0; j < 8; ++j) V[j] = A[j];
    #pragma unroll
    for (int j = 0; j < 8; ++j) V[8 + j] = __shfl(A[j], lane + 1, 64);
    V[16] = __shfl(A[0], lane + 2, 64);
    V[17] = __shfl(A[1], lane + 2, 64);
    #pragma unroll
    for (int j = 0; j < 8; ++j) {
        float o = 0.f;
        #pragma unroll
        for (int k = 0; k < WIN; ++k) o = fmaf(gw.g[k], V[j + k], o);
        out[j] = o;
    }
}

// r19 vs r12 (proven 49.5us): ONLY the launch structure — WPB 4 -> 8
// (512-thread blocks of independent waves, still no barriers/LDS).
// Residency across r12/r18 consistently measured ~45% of the VGPR-tier
// ceiling (7.7/16 and 2.9/8 waves/CU): the common limiter fits ~2
// workgroup slots/CU, not registers. Doubling waves-per-slot should
// double resident waves -> double the TLP covering each load stall.
// VGPR stays ~76 (same accumulator set), so the 4-waves/SIMD tier holds.
__global__ __launch_bounds__(512) void ssim_fused_kernel(
    const float* __restrict__ X, const float* __restrict__ Y,
    double* __restrict__ accum, GaussW gw)
{
    const int wave = threadIdx.x >> 6;
    const int lane = threadIdx.x & 63;

    // Block-level XCD swizzle (bijective: 1128 = 8*141); waves in a block
    // take adjacent row-pairs (shared halo rows hit L1/L2).
    const int id = blockIdx.x;
    const int wb = (id & 7) * BPX + (id >> 3);
    const int P  = wb * WPB + wave;        // global row-pair index
    if (P >= TOTAL_PAIRS) return;          // 48 pad waves; no barriers -> safe

    const int img  = P / NPAIRS;
    const int pair = P % NPAIRS;
    const int r0   = pair * RPW;          // max input row = 372+11 = 383
    const int c0   = lane << 3;           // this lane's 8 columns
    const float* __restrict__ Xb = X + ((size_t)img * IMG_H + r0) * IMG_W + c0;
    const float* __restrict__ Yb = Y + ((size_t)img * IMG_H + r0) * IMG_W + c0;

    // Accumulators: a01 = {m1,m2}, a23 = {xx,yy}, a4 = xy (tensor-packed)
    v2 a01[RPW][8], a23[RPW][8];
    float a4[RPW][8];
    #pragma unroll
    for (int r = 0; r < RPW; ++r)
        #pragma unroll
        for (int j = 0; j < 8; ++j) { a01[r][j] = 0.f; a23[r][j] = 0.f; a4[r][j] = 0.f; }

    #pragma unroll
    for (int k = 0; k < RPW + WIN - 1; ++k) {   // 12 input rows
        const float* rx = Xb + (size_t)k * IMG_W;
        const float* ry = Yb + (size_t)k * IMG_W;
        float4 xa = *(const float4*)(rx);
        float4 xb = *(const float4*)(rx + 4);
        float4 ya = *(const float4*)(ry);
        float4 yb = *(const float4*)(ry + 4);
        v2 p[8] = {{xa.x, ya.x}, {xa.y, ya.y}, {xa.z, ya.z}, {xa.w, ya.w},
                   {xb.x, yb.x}, {xb.y, yb.y}, {xb.z, yb.z}, {xb.w, yb.w}};
        #pragma unroll
        for (int r = 0; r < RPW; ++r) {
            if (k - r >= 0 && k - r < WIN) {     // compile-time after unroll
                v2 g = gw.g[k - r];
                #pragma unroll
                for (int j = 0; j < 8; ++j) {
                    v2 q = p[j];
                    a01[r][j] = __builtin_elementwise_fma(g, q, a01[r][j]);
                    v2 t = g * q;                                  // {gx, gy}
                    a23[r][j] = __builtin_elementwise_fma(t, q, a23[r][j]);
                    a4[r][j]  = fmaf(t.x, q.y, a4[r][j]);          // g*x*y
                }
            }
        }
    }

    // ---- horizontal + epilogue per row ----
    const float C1 = 1e-4f, C2 = 9e-4f;
    float sum = 0.f;
    #pragma unroll
    for (int r = 0; r < RPW; ++r) {
        v2 h01[8], h23[8];
        float h4[8];
        horiz11_v2(a01[r], h01, lane, gw);
        horiz11_v2(a23[r], h23, lane, gw);
        horiz11_f (a4[r],  h4,  lane, gw);
        #pragma unroll
        for (int j = 0; j < 8; ++j) {
            v2 mu = h01[j];
            v2 sq = mu * mu;                    // {mu1², mu2²}
            float m12 = mu.x * mu.y;
            v2 sig = h23[j] - sq;               // {s1, s2}
            float s12 = h4[j] - m12;
            float num = fmaf(2.f, m12, C1) * fmaf(2.f, s12, C2);
            float den = (sq.x + sq.y + C1) * (sig.x + sig.y + C2);
            float ssim = num * __builtin_amdgcn_rcpf(den);
            sum += (c0 + j < OUT_W) ? ssim : 0.f;
        }
    }

    // ---- wave reduction -> one f64 atomic per wave, bucketed ----
    #pragma unroll
    for (int off = 32; off; off >>= 1)
        sum += __shfl_down(sum, off, 64);
    if (lane == 0)
        atomicAdd(&accum[P & (NBUCKETS - 1)], (double)sum);
}

__global__ void ssim_finalize_kernel(const double* __restrict__ accum,
                                     float* __restrict__ out, double inv_count)
{
    const int lane = threadIdx.x;
    double s = 0.0;
    for (int i = lane; i < NBUCKETS; i += 64) s += accum[i];
    #pragma unroll
    for (int off = 32; off; off >>= 1)
        s += __shfl_down(s, off, 64);
    if (lane == 0) out[0] = (float)(1.0 - s * inv_count);
}

extern "C" void kernel_launch(void* const* d_in, const int* in_sizes, int n_in,
                              void* d_out, int out_size, void* d_ws, size_t ws_size,
                              hipStream_t stream) {
    const float* X = (const float*)d_in[0];
    const float* Y = (const float*)d_in[1];
    float* out = (float*)d_out;
    double* accum = (double*)d_ws;

    GaussW gw;
    {
        double g[WIN], ssum = 0.0;
        for (int i = 0; i < WIN; ++i) {
            double d = (double)i - WIN / 2;
            g[i] = exp(-(d * d) / (2.0 * 1.5 * 1.5));
            ssum += g[i];
        }
        for (int i = 0; i < WIN; ++i) gw.g[i] = (float)(g[i] / ssum);
    }

    // d_ws is re-poisoned 0xAA before every call — zero the buckets.
    hipMemsetAsync(accum, 0, NBUCKETS * sizeof(double), stream);

    ssim_fused_kernel<<<NBLOCKS, 64 * WPB, 0, stream>>>(X, Y, accum, gw);

    const double inv_count = 1.0 / ((double)NIMG * OUT_H * OUT_W);
    ssim_finalize_kernel<<<1, 64, 0, stream>>>(accum, out, inv_count);
}

// Round 8
// 123.579 us; speedup vs baseline: 1.9601x; 1.0443x over previous
//
#include <hip/hip_runtime.h>
#include <math.h>

#define WIN 11
#define IMG_H 384
#define IMG_W 512
#define OUT_H (IMG_H - WIN + 1)   // 374
#define OUT_W (IMG_W - WIN + 1)   // 502
#define RPW 2                     // output rows per wave (RPW=4 refuted r18)
#define NPAIRS 187                // per image (exact: 374 = 2*187)
#define NIMG 48
#define TOTAL_PAIRS (NPAIRS * NIMG)   // 8976
#define WPB 4                     // 4 waves/block proven best (8 refuted r19)
#define NBLOCKS 2248              // ceil(8976/4) padded to 8*281 for swizzle
#define BPX 281                   // blocks per XCD
#define NBUCKETS 256

typedef float v2 __attribute__((ext_vector_type(2)));

struct GaussW { float g[WIN]; };
struct Row { float4 xa, xb, ya, yb; };

__device__ __forceinline__ v2 shfl_v2(v2 v, int src) {
    v2 r; r.x = __shfl(v.x, src, 64); r.y = __shfl(v.y, src, 64); return r;
}

__device__ __forceinline__ void horiz11_v2(const v2 (&A)[8], v2 (&out)[8],
                                           int lane, const GaussW& gw)
{
    v2 V[18];
    #pragma unroll
    for (int j = 0; j < 8; ++j) V[j] = A[j];
    #pragma unroll
    for (int j = 0; j < 8; ++j) V[8 + j] = shfl_v2(A[j], lane + 1);
    V[16] = shfl_v2(A[0], lane + 2);
    V[17] = shfl_v2(A[1], lane + 2);
    #pragma unroll
    for (int j = 0; j < 8; ++j) {
        v2 o = 0.f;
        #pragma unroll
        for (int k = 0; k < WIN; ++k) {
            v2 g = gw.g[k];
            o = __builtin_elementwise_fma(g, V[j + k], o);  // v_pk_fma_f32
        }
        out[j] = o;
    }
}

__device__ __forceinline__ void horiz11_f(const float (&A)[8], float (&out)[8],
                                          int lane, const GaussW& gw)
{
    float V[18];
    #pragma unroll
    for (int j = 0; j < 8; ++j) V[j] = A[j];
    #pragma unroll
    for (int j = 0; j < 8; ++j) V[8 + j] = __shfl(A[j], lane + 1, 64);
    V[16] = __shfl(A[0], lane + 2, 64);
    V[17] = __shfl(A[1], lane + 2, 64);
    #pragma unroll
    for (int j = 0; j < 8; ++j) {
        float o = 0.f;
        #pragma unroll
        for (int k = 0; k < WIN; ++k) o = fmaf(gw.g[k], V[j + k], o);
        out[j] = o;
    }
}

// r20 vs r12 (proven 49.5us): ONLY the load schedule. 3-buffer rolling
// lookahead in PLAIN HIP, pinned with sched_barrier(0) fences between row
// phases: region k = {compute row k from buf[k%3]; issue loads of row k+3
// into buf[k%3] (SSA-renamed); fence}. The fence prevents the VGPR-
// minimizing allocator from sinking loads onto their consumers (the r8-r10
// folding failure), guaranteeing >=2 compute phases (~500-900 cy) of lead
// per load -- covering L2/L3 latency -- while the compiler still inserts
// its own correct counted vmcnt waits. No inline asm (r16/r17's container-
// killer parked), no LDS, no barriers, no divergence: waves independent.
// Burst profile per wave: 12-load warmup once, then 4 loads per phase
// instead of r12's 48-load front-loaded burst.
__global__ __launch_bounds__(256) void ssim_fused_kernel(
    const float* __restrict__ X, const float* __restrict__ Y,
    double* __restrict__ accum, GaussW gw)
{
    const int wave = threadIdx.x >> 6;
    const int lane = threadIdx.x & 63;

    // Block-level XCD swizzle; waves in a block take adjacent row-pairs
    // (shared halo rows hit L1/L2).
    const int id = blockIdx.x;
    const int wb = (id & 7) * BPX + (id >> 3);
    const int P  = wb * WPB + wave;        // global row-pair index
    if (P >= TOTAL_PAIRS) return;          // 16 pad waves; no barriers -> safe

    const int img  = P / NPAIRS;
    const int pair = P % NPAIRS;
    const int r0   = pair * RPW;          // max input row = 372+11 = 383
    const int c0   = lane << 3;           // this lane's 8 columns
    const float* __restrict__ Xb = X + ((size_t)img * IMG_H + r0) * IMG_W + c0;
    const float* __restrict__ Yb = Y + ((size_t)img * IMG_H + r0) * IMG_W + c0;

    // Accumulators: a01 = {m1,m2}, a23 = {xx,yy}, a4 = xy (tensor-packed)
    v2 a01[RPW][8], a23[RPW][8];
    float a4[RPW][8];
    #pragma unroll
    for (int r = 0; r < RPW; ++r)
        #pragma unroll
        for (int j = 0; j < 8; ++j) { a01[r][j] = 0.f; a23[r][j] = 0.f; a4[r][j] = 0.f; }

    #define LOADROW(B, K) {                                                  \
        const float* _rx = Xb + (size_t)(K) * IMG_W;                         \
        const float* _ry = Yb + (size_t)(K) * IMG_W;                         \
        (B).xa = *(const float4*)(_rx);                                      \
        (B).xb = *(const float4*)(_rx + 4);                                  \
        (B).ya = *(const float4*)(_ry);                                      \
        (B).yb = *(const float4*)(_ry + 4);                                  \
    }

    Row buf[3];
    LOADROW(buf[0], 0); LOADROW(buf[1], 1); LOADROW(buf[2], 2);  // warm-up
    __builtin_amdgcn_sched_barrier(0);

    #pragma unroll
    for (int k = 0; k < RPW + WIN - 1; ++k) {   // 12 input rows
        Row cur = buf[k % 3];                   // k compile-time: registers
        // Refill this slot with row k+3 (issued in THIS region; consumed
        // 3 regions later -> >=2 fenced compute phases of latency lead).
        if (k + 3 < RPW + WIN - 1) LOADROW(buf[k % 3], k + 3);

        v2 p[8] = {{cur.xa.x, cur.ya.x}, {cur.xa.y, cur.ya.y},
                   {cur.xa.z, cur.ya.z}, {cur.xa.w, cur.ya.w},
                   {cur.xb.x, cur.yb.x}, {cur.xb.y, cur.yb.y},
                   {cur.xb.z, cur.yb.z}, {cur.xb.w, cur.yb.w}};
        #pragma unroll
        for (int r = 0; r < RPW; ++r) {
            if (k - r >= 0 && k - r < WIN) {     // compile-time after unroll
                v2 g = gw.g[k - r];
                #pragma unroll
                for (int j = 0; j < 8; ++j) {
                    v2 q = p[j];
                    a01[r][j] = __builtin_elementwise_fma(g, q, a01[r][j]);
                    v2 t = g * q;                                  // {gx, gy}
                    a23[r][j] = __builtin_elementwise_fma(t, q, a23[r][j]);
                    a4[r][j]  = fmaf(t.x, q.y, a4[r][j]);          // g*x*y
                }
            }
        }
        __builtin_amdgcn_sched_barrier(0);      // phase fence: no load sinking
    }
    #undef LOADROW

    // ---- horizontal + epilogue per row (registers/bpermute only) ----
    const float C1 = 1e-4f, C2 = 9e-4f;
    float sum = 0.f;
    #pragma unroll
    for (int r = 0; r < RPW; ++r) {
        v2 h01[8], h23[8];
        float h4[8];
        horiz11_v2(a01[r], h01, lane, gw);
        horiz11_v2(a23[r], h23, lane, gw);
        horiz11_f (a4[r],  h4,  lane, gw);
        #pragma unroll
        for (int j = 0; j < 8; ++j) {
            v2 mu = h01[j];
            v2 sq = mu * mu;                    // {mu1², mu2²}
            float m12 = mu.x * mu.y;
            v2 sig = h23[j] - sq;               // {s1, s2}
            float s12 = h4[j] - m12;
            float num = fmaf(2.f, m12, C1) * fmaf(2.f, s12, C2);
            float den = (sq.x + sq.y + C1) * (sig.x + sig.y + C2);
            float ssim = num * __builtin_amdgcn_rcpf(den);
            sum += (c0 + j < OUT_W) ? ssim : 0.f;
        }
    }

    // ---- wave reduction -> one f64 atomic per wave, bucketed ----
    #pragma unroll
    for (int off = 32; off; off >>= 1)
        sum += __shfl_down(sum, off, 64);
    if (lane == 0)
        atomicAdd(&accum[P & (NBUCKETS - 1)], (double)sum);
}

__global__ void ssim_finalize_kernel(const double* __restrict__ accum,
                                     float* __restrict__ out, double inv_count)
{
    const int lane = threadIdx.x;
    double s = 0.0;
    for (int i = lane; i < NBUCKETS; i += 64) s += accum[i];
    #pragma unroll
    for (int off = 32; off; off >>= 1)
        s += __shfl_down(s, off, 64);
    if (lane == 0) out[0] = (float)(1.0 - s * inv_count);
}

extern "C" void kernel_launch(void* const* d_in, const int* in_sizes, int n_in,
                              void* d_out, int out_size, void* d_ws, size_t ws_size,
                              hipStream_t stream) {
    const float* X = (const float*)d_in[0];
    const float* Y = (const float*)d_in[1];
    float* out = (float*)d_out;
    double* accum = (double*)d_ws;

    GaussW gw;
    {
        double g[WIN], ssum = 0.0;
        for (int i = 0; i < WIN; ++i) {
            double d = (double)i - WIN / 2;
            g[i] = exp(-(d * d) / (2.0 * 1.5 * 1.5));
            ssum += g[i];
        }
        for (int i = 0; i < WIN; ++i) gw.g[i] = (float)(g[i] / ssum);
    }

    // d_ws is re-poisoned 0xAA before every call — zero the buckets.
    hipMemsetAsync(accum, 0, NBUCKETS * sizeof(double), stream);

    ssim_fused_kernel<<<NBLOCKS, 64 * WPB, 0, stream>>>(X, Y, accum, gw);

    const double inv_count = 1.0 / ((double)NIMG * OUT_H * OUT_W);
    ssim_finalize_kernel<<<1, 64, 0, stream>>>(accum, out, inv_count);
}